// Round 4
// baseline (855.449 us; speedup 1.0000x reference)
//
#include <hip/hip_runtime.h>

typedef __attribute__((ext_vector_type(8))) short short8;
typedef __attribute__((ext_vector_type(16))) float f32x16;

#define CIN   128
#define COUT  256
#define H     112
#define W     112
#define OH    110
#define OW    110
#define KHW   9
#define TH    4
#define TW    32
#define IHH   6               // TH+2
#define IWW   34              // TW+2
#define NPIX  (IHH*IWW)       // 204
#define PPAD  256             // padded pixel dim (pow2 for cheap indexing)
#define X_BYTES (PPAD*CIN*2)  // 65536 B -> 2 blocks/CU

__device__ __forceinline__ short f2b(float f) {
  unsigned u = __builtin_bit_cast(unsigned, f);
  unsigned r = (u + 0x7FFFu + ((u >> 16) & 1u)) >> 16;  // RNE
  return (short)r;
}

// LDS x tile: [pixel p][cin-group G(16)] 16B slots, slot-swizzled G^(p&15),
// identical on write & read (bijective => correct, spreads banks).
// Weights from global wt[khw][cout][cin] (L2-resident), 2-deep reg prefetch.
// MFMA 32x32x16: A row=lane&31(cout), k=(lane>>5)*8+j; B col=lane&31(px);
// C/D: col=lane&31(px), row=(r&3)+8*(r>>2)+4*(lane>>5) (m74/m101).

template<bool USE_WT>
__global__ __launch_bounds__(512, 4)
void conv_main(const float* __restrict__ x, const float* __restrict__ wgt,
               const short* __restrict__ wt, float* __restrict__ out) {
  __shared__ __align__(16) char sx[X_BYTES];

  // XCD-chunked bijective swizzle (grid 3584 % 8 == 0): consecutive tiles
  // (th innermost) share an XCD L2 for halo-row + weight reuse.
  const int nb  = gridDim.x;
  const int swz = (blockIdx.x & 7) * (nb >> 3) + (blockIdx.x >> 3);
  const int b    = swz / 112;          // 4 tw * 28 th = 112 tiles/batch
  const int rem  = swz - b * 112;
  const int t_w  = rem / 28;
  const int t_h  = rem - t_w * 28;
  const int h0 = t_h * TH, w0 = t_w * TW;

  const int tid = threadIdx.x;

  // ---- stage x halo tile: 6x34 pixels x 128 cin, f32 -> bf16 ----
  const float* xb = x + (size_t)b * CIN * (H*W);
  for (int u = tid; u < 16 * PPAD; u += 512) {
    int G = u >> 8, p = u & 255;
    if (p < NPIX) {
      int iy = p / IWW, ix = p - iy * IWW;
      int gy = h0 + iy, gx = w0 + ix;
      short8 v = {0,0,0,0,0,0,0,0};
      if (gy < H && gx < W) {
        const float* s = xb + (size_t)(G*8) * (H*W) + gy * W + gx;
        #pragma unroll
        for (int j = 0; j < 8; ++j) v[j] = f2b(s[j * (H*W)]);
      }
      *(short8*)(sx + p*256 + ((G ^ (p & 15)) << 4)) = v;
    }
  }
  __syncthreads();   // the ONLY barrier

  const int lane = tid & 63;
  const int wid  = tid >> 6;
  const int wm = wid >> 1;        // 0..3 -> couts [wm*64, +64)
  const int wn = wid & 1;         // 0..1 -> rows {wn*2, wn*2+1}
  const int l31 = lane & 31;
  const int lh  = lane >> 5;      // 0/1 -> k-half

  const int aoff = l31 * CIN + lh * 8;          // per-lane A offset (shorts)
  const short* wbase = wt + (size_t)(wm * 64) * CIN;

  f32x16 acc[2][2] = {};

  short8 ab[3][2];   // 2-deep A prefetch ring
  short8 bb[2][2];   // 1-deep B prefetch ring

  auto LA = [&](short8* d, int st) {
    int tap = st >> 3, t = st & 7;
    if (USE_WT) {
      const short* p0 = wbase + tap * (COUT*CIN) + t * 16 + aoff;
      d[0] = *(const short8*)p0;
      d[1] = *(const short8*)(p0 + 32 * CIN);
    } else {
      #pragma unroll
      for (int mi = 0; mi < 2; ++mi) {
        int cout = wm*64 + mi*32 + l31;
        #pragma unroll
        for (int j = 0; j < 8; ++j) {
          int cin = t*16 + lh*8 + j;
          d[mi][j] = f2b(wgt[cout*(CIN*KHW) + cin*KHW + tap]);
        }
      }
    }
  };
  auto LB = [&](short8* d, int st) {
    int tap = st >> 3, t = st & 7;
    int kh = tap / 3, kw = tap - 3 * (tap / 3);
    #pragma unroll
    for (int ni = 0; ni < 2; ++ni) {
      int p = (wn*2 + ni + kh) * IWW + l31 + kw;
      int G = t*2 + lh;
      d[ni] = *(const short8*)(sx + p*256 + ((G ^ (p & 15)) << 4));
    }
  };

  LA(ab[0], 0); LA(ab[1], 1); LB(bb[0], 0);

  #pragma unroll
  for (int st = 0; st < 72; ++st) {          // 9 taps x 8 K16-steps
    if (st + 2 < 72) LA(ab[(st + 2) % 3], st + 2);
    if (st + 1 < 72) LB(bb[(st + 1) & 1], st + 1);
    short8* a = ab[st % 3];
    short8* bf = bb[st & 1];
    #pragma unroll
    for (int mi = 0; mi < 2; ++mi)
      #pragma unroll
      for (int ni = 0; ni < 2; ++ni)
        acc[mi][ni] = __builtin_amdgcn_mfma_f32_32x32x16_bf16(a[mi], bf[ni], acc[mi][ni], 0, 0, 0);
  }

  // ---- epilogue: full 128B-line stores (32 consecutive ow per half-wave) ----
  float* ob = out + (size_t)b * COUT * (OH*OW);
  #pragma unroll
  for (int ni = 0; ni < 2; ++ni) {
    int oh = h0 + wn*2 + ni;
    int ow = w0 + l31;
    if (oh < OH && ow < OW) {
      #pragma unroll
      for (int mi = 0; mi < 2; ++mi) {
        #pragma unroll
        for (int r = 0; r < 16; ++r) {
          int crow = (r & 3) + 8*(r >> 2) + 4*lh;
          int cout = wm*64 + mi*32 + crow;
          ob[cout*(OH*OW) + oh*OW + ow] = acc[mi][ni][r];
        }
      }
    }
  }
}

// one-time weight transpose+cvt: wt[khw][cout][cin] bf16
__global__ void wprep(const float* __restrict__ wgt, short* __restrict__ wt) {
  int idx = blockIdx.x * 256 + threadIdx.x;
  if (idx >= KHW*COUT*CIN) return;
  int khw  = idx / (COUT*CIN);
  int rem  = idx - khw*(COUT*CIN);
  int cout = rem >> 7, cin = rem & 127;
  wt[idx] = f2b(wgt[cout*(CIN*KHW) + cin*KHW + khw]);
}

extern "C" void kernel_launch(void* const* d_in, const int* in_sizes, int n_in,
                              void* d_out, int out_size, void* d_ws, size_t ws_size,
                              hipStream_t stream) {
  const float* x   = (const float*)d_in[0];
  const float* wgt = (const float*)d_in[1];
  float* out = (float*)d_out;
  const size_t wt_bytes = (size_t)(KHW*COUT*CIN) * sizeof(short);
  dim3 grid(28 * 4 * 32);   // th(28) x tw(4) x batch(32) = 3584 blocks
  if (ws_size >= wt_bytes) {
    short* wt = (short*)d_ws;
    wprep<<<(KHW*COUT*CIN + 255)/256, 256, 0, stream>>>(wgt, wt);
    conv_main<true><<<grid, 512, 0, stream>>>(x, wgt, wt, out);
  } else {
    conv_main<false><<<grid, 512, 0, stream>>>(x, wgt, nullptr, out);
  }
}

// Round 5
// 344.319 us; speedup vs baseline: 2.4845x; 2.4845x over previous
//
#include <hip/hip_runtime.h>

typedef __attribute__((ext_vector_type(8))) short short8;
typedef __attribute__((ext_vector_type(4))) float f32x4;

#define CIN   128
#define COUT  256
#define H     112
#define W     112
#define OH    110
#define OW    110
#define KHW   9
#define TH    8
#define TW    32
#define IHH   10              // TH+2
#define IWW   34              // TW+2
#define NPIX  340             // IHH*IWW
#define XB    (NPIX*128)      // x half-tile: 340 px * 8 slots * 16B = 43520
#define WB    16384           // w tap-half: 128 cout * 8 slots * 16B

__device__ __forceinline__ short f2b(float f) {
  unsigned u = __builtin_bit_cast(unsigned, f);
  unsigned r = (u + 0x7FFFu + ((u >> 16) & 1u)) >> 16;  // RNE
  return (short)r;
}

typedef unsigned int u32;
__device__ __forceinline__ void gload16(const void* g, void* l) {
  __builtin_amdgcn_global_load_lds(
      (const __attribute__((address_space(1))) u32*)g,
      (__attribute__((address_space(3))) u32*)l, 16, 0, 0);
}

// LDS layouts (16B slots, XOR-swizzled; involution applied on write-source
// and read identically => bijective => correct):
//   x: sx[p][G0..7]   byte = p*128  + ((G ^ (p&7))<<4)
//   w: sw[c][Gh0..7]  byte = c*128  + ((Gh^ (c&7))<<4)   (c = block-local cout)
// w staged via global_load_lds (linear dest, pre-swizzled source).
// Pipeline: stage tap t+1 BEFORE computing tap t; one __syncthreads per tap
// (drains vmcnt) -> loads in flight under MFMA; 2 blocks/CU cover the drain.

template<bool USE_WT>
__global__ __launch_bounds__(512, 4)
void conv_main(const float* __restrict__ x, const float* __restrict__ wgt,
               const short* __restrict__ wt, float* __restrict__ out) {
  __shared__ __align__(16) char smem[XB + 2*WB];   // 76288 B -> 2 blocks/CU
  char* sx = smem;
  char* sw = smem + XB;

  const int tid = threadIdx.x;

  // XCD-chunked bijective swizzle (3584 % 8 == 0); t_h fastest -> neighbors
  // share halo rows + weight chunks in the same XCD L2.
  const int nb  = gridDim.x;
  const int swz = (blockIdx.x & 7) * (nb >> 3) + (blockIdx.x >> 3);
  const int b    = swz / 112;            // 2 cblk * 4 tw * 14 th
  const int rem  = swz - b * 112;
  const int cblk = rem / 56;
  const int rem2 = rem - cblk * 56;
  const int t_w  = rem2 / 14;
  const int t_h  = rem2 - t_w * 14;
  const int h0 = t_h * TH, w0 = t_w * TW;

  const float* xb = x + (size_t)b * CIN * (H*W);

  auto stage_x = [&](int hh) {
    const float* xh = xb + (size_t)(hh * 64) * (H*W);
    for (int u = tid; u < 8 * NPIX; u += 512) {
      int G = u / NPIX, p = u - G * NPIX;
      int iy = p / IWW, ix = p - iy * IWW;
      int gy = h0 + iy, gx = w0 + ix;
      short8 v = {0,0,0,0,0,0,0,0};
      if (gy < H && gx < W) {
        const float* s = xh + (size_t)(G*8) * (H*W) + gy * W + gx;
        #pragma unroll
        for (int j = 0; j < 8; ++j) v[j] = f2b(s[j * (H*W)]);
      }
      *(short8*)(sx + p*128 + ((G ^ (p & 7)) << 4)) = v;
    }
  };

  auto stage_w = [&](int st, int buf) {
    int hh = st / 9, tap = st - hh * 9;
    if (USE_WT) {
      const short* base = wt + (size_t)tap * (COUT*CIN)
                             + (size_t)(cblk*128) * CIN + hh * 64;
      #pragma unroll
      for (int it = 0; it < 2; ++it) {
        int slot = it * 512 + tid;            // 1024 slots of 16B
        int c = slot >> 3, gsw = (slot & 7) ^ (c & 7);
        gload16(base + c * CIN + gsw * 8, sw + buf*WB + slot * 16);
      }
    } else {
      #pragma unroll
      for (int it = 0; it < 2; ++it) {
        int slot = it * 512 + tid;
        int c = slot >> 3, gsw = (slot & 7) ^ (c & 7);
        int cout = cblk*128 + c;
        short8 v;
        #pragma unroll
        for (int j = 0; j < 8; ++j) {
          int cin = hh*64 + gsw*8 + j;
          v[j] = f2b(wgt[cout*(CIN*KHW) + cin*KHW + (st - hh*9)]);
        }
        *(short8*)(sw + buf*WB + slot * 16) = v;
      }
    }
  };

  const int lane = tid & 63;
  const int wid  = tid >> 6;
  const int wm = wid >> 2;        // 0..1 -> couts [wm*64, +64) of block's 128
  const int wn = wid & 3;         // 0..3 -> rows {2wn, 2wn+1}
  const int l15 = lane & 15;
  const int kgrp = lane >> 4;     // 0..3

  f32x4 acc[4][4] = {};

  stage_x(0);
  stage_w(0, 0);
  __syncthreads();

  for (int st = 0; st < 18; ++st) {          // 2 cin-halves x 9 taps
    if (st + 1 < 18) stage_w(st + 1, (st + 1) & 1);

    const int tap = st % 9;
    const int kh = tap / 3, kw = tap - (tap/3)*3;
    const char* swb = sw + (st & 1) * WB;

    #pragma unroll
    for (int s = 0; s < 2; ++s) {            // two K=32 steps over 64 cins
      const int g = s*4 + kgrp;
      const int aslot = (g ^ (l15 & 7)) << 4;
      short8 a[4];
      #pragma unroll
      for (int mi = 0; mi < 4; ++mi)
        a[mi] = *(const short8*)(swb + (wm*64 + mi*16 + l15) * 128 + aslot);
      short8 bf[4];
      #pragma unroll
      for (int ni = 0; ni < 4; ++ni) {
        int p = (2*wn + (ni >> 1) + kh) * IWW + (ni & 1)*16 + l15 + kw;
        bf[ni] = *(const short8*)(sx + p*128 + ((g ^ (p & 7)) << 4));
      }
      #pragma unroll
      for (int mi = 0; mi < 4; ++mi)
        #pragma unroll
        for (int ni = 0; ni < 4; ++ni)
          acc[mi][ni] = __builtin_amdgcn_mfma_f32_16x16x32_bf16(a[mi], bf[ni], acc[mi][ni], 0, 0, 0);
    }

    if (st == 8) {
      __syncthreads();      // x half-0 readers done; w buf1 (st=9) also drained
      stage_x(1);
      __syncthreads();      // x half-1 ready
    } else {
      __syncthreads();      // w(st+1) staged + buf[(st+1)&1] readers done
    }
  }

  // ---- epilogue: C layout col=l15 (px), row=4*kgrp+r (cout) [m89] ----
  float* ob = out + (size_t)b * COUT * (OH*OW);
  #pragma unroll
  for (int ni = 0; ni < 4; ++ni) {
    int oh = h0 + 2*wn + (ni >> 1);
    int ow = w0 + (ni & 1)*16 + l15;
    if (oh < OH && ow < OW) {
      #pragma unroll
      for (int mi = 0; mi < 4; ++mi) {
        #pragma unroll
        for (int r = 0; r < 4; ++r) {
          int cout = cblk*128 + wm*64 + mi*16 + kgrp*4 + r;
          ob[(size_t)cout*(OH*OW) + oh*OW + ow] = acc[mi][ni][r];
        }
      }
    }
  }
}

// one-time weight transpose+cvt: wt[tap][cout][cin] bf16
__global__ void wprep(const float* __restrict__ wgt, short* __restrict__ wt) {
  int idx = blockIdx.x * 256 + threadIdx.x;
  if (idx >= KHW*COUT*CIN) return;
  int khw  = idx / (COUT*CIN);
  int rem  = idx - khw*(COUT*CIN);
  int cout = rem >> 7, cin = rem & 127;
  wt[idx] = f2b(wgt[cout*(CIN*KHW) + cin*KHW + khw]);
}

extern "C" void kernel_launch(void* const* d_in, const int* in_sizes, int n_in,
                              void* d_out, int out_size, void* d_ws, size_t ws_size,
                              hipStream_t stream) {
  const float* x   = (const float*)d_in[0];
  const float* wgt = (const float*)d_in[1];
  float* out = (float*)d_out;
  const size_t wt_bytes = (size_t)(KHW*COUT*CIN) * sizeof(short);
  dim3 grid(3584);   // 2 cblk x 4 tw x 14 th x 32 b
  if (ws_size >= wt_bytes) {
    short* wt = (short*)d_ws;
    wprep<<<(KHW*COUT*CIN + 255)/256, 256, 0, stream>>>(wgt, wt);
    conv_main<true><<<grid, 512, 0, stream>>>(x, wgt, wt, out);
  } else {
    conv_main<false><<<grid, 512, 0, stream>>>(x, wgt, nullptr, out);
  }
}